// Round 1
// baseline (490.637 us; speedup 1.0000x reference)
//
#include <hip/hip_runtime.h>
#include <math.h>

// Problem constants (from setup_inputs)
#define NN 100000            // nodes
#define NE 1600000           // real edges
#define ET (NE + NN)         // edges + self loops = 1,700,000
#define FIN 128
#define H1 4
#define C1 8
#define F1 32                // H1*C1
#define FOUT 16
#define NSLOPE 0.2f
#define NB_SCAN ((NN + 255) / 256)   // 391

// ---------------- CSR build ----------------

__global__ __launch_bounds__(256) void k_count(const int* __restrict__ dstA, int* __restrict__ deg) {
    int e = blockIdx.x * 256 + threadIdx.x;
    if (e < NE) atomicAdd(&deg[dstA[e]], 1);
}

__global__ __launch_bounds__(256) void k_scan_a(const int* __restrict__ deg, int* __restrict__ bsum) {
    __shared__ int s[256];
    int t = threadIdx.x;
    int n = blockIdx.x * 256 + t;
    int v = (n < NN) ? deg[n] + 1 : 0;   // +1: self loop
    s[t] = v; __syncthreads();
    for (int off = 128; off > 0; off >>= 1) {
        if (t < off) s[t] += s[t + off];
        __syncthreads();
    }
    if (t == 0) bsum[blockIdx.x] = s[0];
}

__global__ __launch_bounds__(512) void k_scan_b(const int* __restrict__ bsum, int* __restrict__ boff) {
    __shared__ int s[512];
    int t = threadIdx.x;
    int v = (t < NB_SCAN) ? bsum[t] : 0;
    s[t] = v; __syncthreads();
    for (int off = 1; off < 512; off <<= 1) {
        int xv = (t >= off) ? s[t - off] : 0;
        __syncthreads();
        s[t] += xv;
        __syncthreads();
    }
    if (t < NB_SCAN) boff[t] = s[t] - v;  // exclusive
}

__global__ __launch_bounds__(256) void k_scan_c(const int* __restrict__ deg, const int* __restrict__ boff,
                                                int* __restrict__ rowstart, int* __restrict__ cursor) {
    __shared__ int s[256];
    int t = threadIdx.x;
    int n = blockIdx.x * 256 + t;
    int v = (n < NN) ? deg[n] + 1 : 0;
    s[t] = v; __syncthreads();
    for (int off = 1; off < 256; off <<= 1) {
        int xv = (t >= off) ? s[t - off] : 0;
        __syncthreads();
        s[t] += xv;
        __syncthreads();
    }
    int incl = s[t];
    int excl = incl - v;
    int base = boff[blockIdx.x];
    if (n < NN) { rowstart[n] = base + excl; cursor[n] = base + excl; }
    if (n == NN - 1) rowstart[NN] = base + incl;  // == ET
}

__global__ __launch_bounds__(256) void k_scatter(const int* __restrict__ srcA, const int* __restrict__ dstA,
                                                 int* __restrict__ cursor, int* __restrict__ esrc) {
    int e = blockIdx.x * 256 + threadIdx.x;
    if (e >= ET) return;
    int s, d;
    if (e < NE) { s = srcA[e]; d = dstA[e]; }
    else        { s = e - NE;  d = s; }        // self loop
    int pos = atomicAdd(&cursor[d], 1);
    esrc[pos] = s;
}

// ---------------- Layer 1: x@W1 + attention coefficients ----------------

__global__ __launch_bounds__(256) void k_gemm1(const float* __restrict__ x, const float* __restrict__ W1,
        const float* __restrict__ a1s, const float* __restrict__ a1d,
        float* __restrict__ xw1, float* __restrict__ as1, float* __restrict__ ad1) {
    int n = blockIdx.x * 256 + threadIdx.x;
    if (n >= NN) return;
    float acc[F1];
#pragma unroll
    for (int c = 0; c < F1; c++) acc[c] = 0.f;
    const float4* x4 = (const float4*)(x + (size_t)n * FIN);
#pragma unroll 4
    for (int k4 = 0; k4 < FIN / 4; k4++) {
        float4 xv = x4[k4];
        float xk[4] = {xv.x, xv.y, xv.z, xv.w};
#pragma unroll
        for (int kk = 0; kk < 4; kk++) {
            int k = k4 * 4 + kk;
#pragma unroll
            for (int c = 0; c < F1; c++)
                acc[c] = fmaf(xk[kk], W1[k * F1 + c], acc[c]);  // W1 addr wave-uniform -> s_load
        }
    }
    float4* o4 = (float4*)(xw1 + (size_t)n * F1);
#pragma unroll
    for (int c4 = 0; c4 < F1 / 4; c4++)
        o4[c4] = make_float4(acc[c4*4], acc[c4*4+1], acc[c4*4+2], acc[c4*4+3]);
#pragma unroll
    for (int h = 0; h < H1; h++) {
        float ss = 0.f, dd = 0.f;
#pragma unroll
        for (int c = 0; c < C1; c++) {
            ss = fmaf(acc[h*C1+c], a1s[h*C1+c], ss);
            dd = fmaf(acc[h*C1+c], a1d[h*C1+c], dd);
        }
        as1[n*H1+h] = ss;
        ad1[n*H1+h] = dd;
    }
}

// ---------------- Layer 1: gather softmax-aggregate + bias + ELU ----------------
// 32 lanes per node (8 nodes / 256-block); lane owns channel c, head h=c>>3.
// Softmax without max-subtraction: alpha = exp(e)/sum(exp(e)) (no overflow, |e|<~10).

__global__ __launch_bounds__(256) void k_gather1(const int* __restrict__ rowstart, const int* __restrict__ esrc,
        const float* __restrict__ as1, const float* __restrict__ ad1,
        const float* __restrict__ xw1, const float* __restrict__ b1,
        float* __restrict__ h1) {
    int n = blockIdx.x * 8 + (threadIdx.x >> 5);
    if (n >= NN) return;
    int c = threadIdx.x & 31;
    int h = c >> 3;
    float adh = ad1[n * H1 + h];
    int beg = rowstart[n], end = rowstart[n + 1];
    float accn = 0.f, accd = 0.f;
    for (int i = beg; i < end; i++) {
        int s = esrc[i];
        float e = as1[s * H1 + h] + adh;
        e = (e > 0.f) ? e : NSLOPE * e;
        float ee = __expf(e);
        accd += ee;
        accn = fmaf(ee, xw1[(size_t)s * F1 + c], accn);
    }
    float y = accn / accd + b1[c];
    y = (y > 0.f) ? y : expm1f(y);   // ELU
    h1[(size_t)n * F1 + c] = y;
}

// ---------------- Layer 2: h1@W2 + attention coefficients ----------------

__global__ __launch_bounds__(256) void k_node2(const float* __restrict__ h1, const float* __restrict__ W2,
        const float* __restrict__ a2s, const float* __restrict__ a2d,
        float* __restrict__ xw2, float* __restrict__ as2, float* __restrict__ ad2) {
    int n = blockIdx.x * 256 + threadIdx.x;
    if (n >= NN) return;
    float acc[FOUT];
#pragma unroll
    for (int j = 0; j < FOUT; j++) acc[j] = 0.f;
    const float4* h4 = (const float4*)(h1 + (size_t)n * F1);
#pragma unroll
    for (int i4 = 0; i4 < F1 / 4; i4++) {
        float4 hv = h4[i4];
        float hk[4] = {hv.x, hv.y, hv.z, hv.w};
#pragma unroll
        for (int kk = 0; kk < 4; kk++) {
            int i = i4 * 4 + kk;
#pragma unroll
            for (int j = 0; j < FOUT; j++)
                acc[j] = fmaf(hk[kk], W2[i * FOUT + j], acc[j]);
        }
    }
    float ss = 0.f, dd = 0.f;
#pragma unroll
    for (int j = 0; j < FOUT; j++) {
        ss = fmaf(acc[j], a2s[j], ss);
        dd = fmaf(acc[j], a2d[j], dd);
    }
    float4* o4 = (float4*)(xw2 + (size_t)n * FOUT);
#pragma unroll
    for (int j4 = 0; j4 < FOUT / 4; j4++)
        o4[j4] = make_float4(acc[j4*4], acc[j4*4+1], acc[j4*4+2], acc[j4*4+3]);
    as2[n] = ss;
    ad2[n] = dd;
}

// ---------------- Layer 2: gather softmax-aggregate + bias + log_softmax ----------------
// 16 lanes per node (16 nodes / 256-block); lane owns output class c.

__global__ __launch_bounds__(256) void k_gather2(const int* __restrict__ rowstart, const int* __restrict__ esrc,
        const float* __restrict__ as2, const float* __restrict__ ad2,
        const float* __restrict__ xw2, const float* __restrict__ b2,
        float* __restrict__ out) {
    int n = blockIdx.x * 16 + (threadIdx.x >> 4);
    if (n >= NN) return;
    int c = threadIdx.x & 15;
    float adn = ad2[n];
    int beg = rowstart[n], end = rowstart[n + 1];
    float accn = 0.f, accd = 0.f;
    for (int i = beg; i < end; i++) {
        int s = esrc[i];
        float e = as2[s] + adn;
        e = (e > 0.f) ? e : NSLOPE * e;
        float ee = __expf(e);
        accd += ee;
        accn = fmaf(ee, xw2[(size_t)s * FOUT + c], accn);
    }
    float y = accn / accd + b2[c];
    // log_softmax across the 16 lanes of this node group
    float m = y;
#pragma unroll
    for (int off = 8; off > 0; off >>= 1) m = fmaxf(m, __shfl_xor(m, off));
    float ex = __expf(y - m);
    float sum = ex;
#pragma unroll
    for (int off = 8; off > 0; off >>= 1) sum += __shfl_xor(sum, off);
    out[(size_t)n * FOUT + c] = y - m - logf(sum);
}

// ---------------- launch ----------------

extern "C" void kernel_launch(void* const* d_in, const int* in_sizes, int n_in,
                              void* d_out, int out_size, void* d_ws, size_t ws_size,
                              hipStream_t stream) {
    const float* x   = (const float*)d_in[0];
    const int*   ei  = (const int*)d_in[1];
    const float* W1  = (const float*)d_in[2];
    const float* a1s = (const float*)d_in[3];
    const float* a1d = (const float*)d_in[4];
    const float* b1  = (const float*)d_in[5];
    const float* W2  = (const float*)d_in[6];
    const float* a2s = (const float*)d_in[7];
    const float* a2d = (const float*)d_in[8];
    const float* b2  = (const float*)d_in[9];
    float* out = (float*)d_out;

    const int* srcA = ei;        // edge_index[0]
    const int* dstA = ei + NE;   // edge_index[1]

    char* w = (char*)d_ws;
    size_t off = 0;
    auto carve = [&](size_t bytes) -> void* {
        void* p = w + off;
        off = (off + bytes + 255) & ~(size_t)255;
        return p;
    };
    float* xw1     = (float*)carve((size_t)NN * F1 * 4);     // 12.8 MB
    float* as1     = (float*)carve((size_t)NN * H1 * 4);
    float* ad1     = (float*)carve((size_t)NN * H1 * 4);
    float* h1      = (float*)carve((size_t)NN * F1 * 4);     // 12.8 MB
    float* xw2     = (float*)carve((size_t)NN * FOUT * 4);   // 6.4 MB
    float* as2     = (float*)carve((size_t)NN * 4);
    float* ad2     = (float*)carve((size_t)NN * 4);
    int* deg       = (int*)carve((size_t)NN * 4);
    int* rowstart  = (int*)carve((size_t)(NN + 1) * 4);
    int* cursor    = (int*)carve((size_t)NN * 4);
    int* esrc      = (int*)carve((size_t)ET * 4);            // 6.8 MB
    int* bsum      = (int*)carve((size_t)NB_SCAN * 4);
    int* boff      = (int*)carve((size_t)NB_SCAN * 4);
    (void)ws_size; (void)in_sizes; (void)n_in; (void)out_size;

    hipMemsetAsync(deg, 0, (size_t)NN * 4, stream);

    k_count  <<<(NE + 255) / 256, 256, 0, stream>>>(dstA, deg);
    k_scan_a <<<NB_SCAN, 256, 0, stream>>>(deg, bsum);
    k_scan_b <<<1, 512, 0, stream>>>(bsum, boff);
    k_scan_c <<<NB_SCAN, 256, 0, stream>>>(deg, boff, rowstart, cursor);
    k_scatter<<<(ET + 255) / 256, 256, 0, stream>>>(srcA, dstA, cursor, esrc);

    k_gemm1  <<<(NN + 255) / 256, 256, 0, stream>>>(x, W1, a1s, a1d, xw1, as1, ad1);
    k_gather1<<<(NN + 7) / 8, 256, 0, stream>>>(rowstart, esrc, as1, ad1, xw1, b1, h1);
    k_node2  <<<(NN + 255) / 256, 256, 0, stream>>>(h1, W2, a2s, a2d, xw2, as2, ad2);
    k_gather2<<<(NN + 15) / 16, 256, 0, stream>>>(rowstart, esrc, as2, ad2, xw2, b2, out);
}